// Round 8
// baseline (778.264 us; speedup 1.0000x reference)
//
#include <hip/hip_runtime.h>
#include <stdint.h>

#define B_   16
#define C_   192
#define TX_  512
#define TY_  2048
#define K_   384       // 2*C
#define SEG_ 32
#define NEG_INF_ (-1e9f)

// Output layout (floats) in d_out:
//   z_slice : [16,192,32]    @ 0         (98304)
//   ids     : [16] (as f32)  @ 98304     (16)
//   attn    : [16,2048,512]  @ 98320     (16777216)
//   m_p_a   : [16,192,2048]  @ 16875536  (6291456)
//   logs_p_a: [16,192,2048]  @ 23166992  (6291456)

// ---------------------------------------------------------------------------
// K0: build B-matrix [b, k, tx] (k<192: s = exp(-2 logs); k>=192: s*m_p) and
//     c_term[b,tx] = sum_c (-0.5 s m^2 - logs)
// ---------------------------------------------------------------------------
__global__ __launch_bounds__(128) void k_prep(const float* __restrict__ mp,
                                              const float* __restrict__ logsp,
                                              float* __restrict__ Bmat,
                                              float* __restrict__ cterm) {
    int b  = blockIdx.y;
    int tx = blockIdx.x * 128 + threadIdx.x;
    const float* mb = mp    + (size_t)b * C_ * TX_ + tx;
    const float* lb = logsp + (size_t)b * C_ * TX_ + tx;
    float* B0 = Bmat + (size_t)b * K_ * TX_ + tx;
    float acc = 0.f;
    for (int c = 0; c < C_; ++c) {
        float lg = lb[(size_t)c * TX_];
        float m  = mb[(size_t)c * TX_];
        float s  = expf(-2.f * lg);
        B0[(size_t)c * TX_]        = s;
        B0[(size_t)(C_ + c) * TX_] = s * m;
        acc += -0.5f * s * m * m - lg;
    }
    cterm[b * TX_ + tx] = acc;
}

// ---------------------------------------------------------------------------
// K1: neg_cent GEMM.  C[b, ty, tx] = sum_k A[b,k,ty]*B[b,k,tx] + cterm[b,tx]
//     A is derived on the fly from z_p: k<192 -> -0.5*z^2 ; k>=192 -> z.
//     128x128 tile, 256 threads, 8x8 accumulators/thread, K-block 16.
// ---------------------------------------------------------------------------
__global__ __launch_bounds__(256) void k_gemm(const float* __restrict__ zp,
                                              const float* __restrict__ Bmat,
                                              const float* __restrict__ cterm,
                                              float* __restrict__ ncout) {
    __shared__ float As[16][128];
    __shared__ float Bs[16][128];
    int b  = blockIdx.z;
    int m0 = blockIdx.y * 128;   // ty
    int n0 = blockIdx.x * 128;   // tx
    int tid = threadIdx.x;
    int tm = tid >> 4;           // 0..15
    int tn = tid & 15;           // 0..15
    const float* zpb = zp   + (size_t)b * C_ * TY_;
    const float* Bb  = Bmat + (size_t)b * K_ * TX_;

    float acc[8][8];
#pragma unroll
    for (int i = 0; i < 8; ++i)
#pragma unroll
        for (int j = 0; j < 8; ++j) acc[i][j] = 0.f;

    int lrow = tid >> 5;           // 0..7
    int lcol = (tid & 31) << 2;    // 0..124

    for (int k0 = 0; k0 < K_; k0 += 16) {
        int ksrc = (k0 < C_) ? k0 : (k0 - C_);
        const float* Ab = zpb + (size_t)(ksrc + lrow) * TY_ + m0 + lcol;
        float4 z0 = *(const float4*)Ab;
        float4 z1 = *(const float4*)(Ab + (size_t)8 * TY_);
        if (k0 < C_) {
            z0.x = -0.5f * z0.x * z0.x; z0.y = -0.5f * z0.y * z0.y;
            z0.z = -0.5f * z0.z * z0.z; z0.w = -0.5f * z0.w * z0.w;
            z1.x = -0.5f * z1.x * z1.x; z1.y = -0.5f * z1.y * z1.y;
            z1.z = -0.5f * z1.z * z1.z; z1.w = -0.5f * z1.w * z1.w;
        }
        const float* Bp = Bb + (size_t)(k0 + lrow) * TX_ + n0 + lcol;
        float4 w0 = *(const float4*)Bp;
        float4 w1 = *(const float4*)(Bp + (size_t)8 * TX_);

        __syncthreads();   // prior iteration's reads done before overwrite
        *(float4*)&As[lrow][lcol]     = z0;
        *(float4*)&As[lrow + 8][lcol] = z1;
        *(float4*)&Bs[lrow][lcol]     = w0;
        *(float4*)&Bs[lrow + 8][lcol] = w1;
        __syncthreads();

#pragma unroll
        for (int kk = 0; kk < 16; ++kk) {
            float4 a0 = *(const float4*)&As[kk][tm * 8];
            float4 a1 = *(const float4*)&As[kk][tm * 8 + 4];
            float4 b0 = *(const float4*)&Bs[kk][tn * 8];
            float4 b1 = *(const float4*)&Bs[kk][tn * 8 + 4];
            float a[8]  = {a0.x, a0.y, a0.z, a0.w, a1.x, a1.y, a1.z, a1.w};
            float bb[8] = {b0.x, b0.y, b0.z, b0.w, b1.x, b1.y, b1.z, b1.w};
#pragma unroll
            for (int i = 0; i < 8; ++i)
#pragma unroll
                for (int j = 0; j < 8; ++j)
                    acc[i][j] = fmaf(a[i], bb[j], acc[i][j]);
        }
    }

    float cadd[8];
#pragma unroll
    for (int j = 0; j < 8; ++j) cadd[j] = cterm[b * TX_ + n0 + tn * 8 + j];

#pragma unroll
    for (int i = 0; i < 8; ++i) {
        int row = m0 + tm * 8 + i;
        float* orow = ncout + ((size_t)b * TY_ + row) * TX_ + n0 + tn * 8;
        float4 o0, o1;
        o0.x = acc[i][0] + cadd[0]; o0.y = acc[i][1] + cadd[1];
        o0.z = acc[i][2] + cadd[2]; o0.w = acc[i][3] + cadd[3];
        o1.x = acc[i][4] + cadd[4]; o1.y = acc[i][5] + cadd[5];
        o1.z = acc[i][6] + cadd[6]; o1.w = acc[i][7] + cadd[7];
        *(float4*)orow       = o0;
        *(float4*)(orow + 4) = o1;
    }
}

// ---------------------------------------------------------------------------
// K2: fused DP forward + backward. Barrier-phased, batched-issue (r8).
//
// History: r0 496, r6 497, r7 ~460 cyc/row — all three had per-row EXPOSED
// load latency. r7's smoking gun: VGPR_Count=32 despite float4 q[16] (needs
// 64 VGPRs) -> the scheduler sank each ds_read_b128 to just before its row
// (minimizing pressure), so every row paid ~120 cyc LDS latency + lone-wave
// VALU issue on ~43 ops. m134 proves a single wave CAN pipeline ds_reads at
// ~12 cyc/b128 — the schedule just never asked.
//
// r8: (a) sched_barrier(0) after each 16-read block pins all 16 ds_read
// issues BEFORE the dependent compute (compiler's counted lgkmcnt covers
// consumption); (b) named register buffers qa/qb, 2-group double buffer,
// fully static unroll (no runtime-indexed arrays -> no scratch); (c)
// producers 8->4 waves (block 320 = 5 waves -> max 2 waves/SIMD -> 256-VGPR
// budget; qa+qb=128 regs + state fits; a 9-wave block would cap at ~170).
// Each producer stages 8 rows/phase (16 loads + 16 ds_writes, <=1000 cyc,
// hidden under consumer ~3000/phase). Consumer processes all 4 groups of a
// phase unconditionally — rows >= t_y are provably harmless (their dirn
// bits are never consulted; v is never reused after the last real row).
//
// LDS = 2 x 64KB halves (32 rows x 2KB). Phase sg: producers fill half
// (sg+1)&1, consumer drains half sg&1, one barrier per phase.
// Dirn bits -> gdirs (= m_p_a region, overwritten later by k_proj);
// stores drain once per phase at the barrier. After forward, all waves
// copy gdirs into LDS (original layout); proven backward walk unchanged.
// ---------------------------------------------------------------------------
#if __has_builtin(__builtin_amdgcn_update_dpp)
// wave_shr:1 (dpp_ctrl 0x138): lane L <- lane L-1; lane 0 <- old (=NEG_INF).
#define LEFT_OF(v7)                                                          \
    __int_as_float(__builtin_amdgcn_update_dpp(                              \
        __float_as_int(NEG_INF_), __float_as_int(v7), 0x138, 0xF, 0xF, false))
#else
#define LEFT_OF(v7)                                                         \
    ({ float _l = __shfl_up((v7), 1); if (lane == 0) _l = NEG_INF_; _l; })
#endif

// 16x ds_read_b128 of group (goff) into named buffer Q, batch-issued.
#define LOADQ(Q, hb, goff)                                                   \
    {                                                                        \
        const float* _p = (hb) + (goff) * 4096;                              \
        _Pragma("unroll") for (int r = 0; r < 8; ++r) {                      \
            Q[2 * r]     = *(const float4*)(_p + r * 512);                   \
            Q[2 * r + 1] = *(const float4*)(_p + r * 512 + 256);             \
        }                                                                    \
    }                                                                        \
    __builtin_amdgcn_sched_barrier(0);   // pin the 16 issues above compute

#define PROCQ(Q, gidx)                                                       \
    {                                                                        \
        unsigned dw0 = 0u, dw1 = 0u;                                         \
        _Pragma("unroll") for (int r = 0; r < 8; ++r) {                      \
            float rc[8] = {Q[2 * r].x,     Q[2 * r].y,                       \
                           Q[2 * r].z,     Q[2 * r].w,                       \
                           Q[2 * r + 1].x, Q[2 * r + 1].y,                   \
                           Q[2 * r + 1].z, Q[2 * r + 1].w};                  \
            float left = LEFT_OF(v[7]);                                      \
            unsigned by = 0u;                                                \
            _Pragma("unroll") for (int k = 7; k >= 0; --k) {                 \
                float vs = (k == 0) ? left : v[k - 1];                       \
                if (vs > v[k]) by |= (1u << k);                              \
                v[k] = fmaxf(v[k], vs) + rc[k];                              \
            }                                                                \
            if (r < 4) dw0 |= by << (8 * r);                                 \
            else       dw1 |= by << (8 * (r - 4));                           \
        }                                                                    \
        gd32[(2 * (gidx))     * 64 + lane] = (int)dw0;                       \
        gd32[(2 * (gidx) + 1) * 64 + lane] = (int)dw1;                       \
    }

__global__ __launch_bounds__(320, 2) void k_dp(const float* __restrict__ nc,
                                               const int* __restrict__ xl,
                                               const int* __restrict__ yl,
                                               int* __restrict__ path,
                                               int* __restrict__ gdirs) {
    extern __shared__ unsigned char sdirs[];   // 131072 B: 2 x 64KB halves
    float* stage = (float*)sdirs;              // half h at float offset h*16384
    int b    = blockIdx.x;
    int tid  = threadIdx.x;
    int wid  = tid >> 6;                       // 0 = consumer, 1..4 producers
    int lane = tid & 63;
    int t_x  = xl[b];
    int t_y  = yl[b]; if (t_y > TY_) t_y = TY_;
    const float* ncb = nc + (size_t)b * TY_ * TX_;
    int* gd32 = gdirs + b * (TY_ * 64 / 4);    // 32768 dwords per block

    int nsg = (t_y + 31) >> 5;                 // 32-row phases

    // ---- prologue: producers fill half 0 with rows 0..31 (8 rows each) ----
    if (wid > 0) {
        int w = wid - 1;
        float* lb = stage + (8 * w) * 512 + lane * 4;
        const float* gp = ncb + (size_t)(8 * w) * TX_ + lane * 8;
        float4 t[16];
#pragma unroll
        for (int r = 0; r < 8; ++r) {
            t[2 * r]     = *(const float4*)(gp + (size_t)r * TX_);
            t[2 * r + 1] = *(const float4*)(gp + (size_t)r * TX_ + 4);
        }
#pragma unroll
        for (int r = 0; r < 8; ++r) {
            *(float4*)(lb + r * 512)       = t[2 * r];
            *(float4*)(lb + r * 512 + 256) = t[2 * r + 1];
        }
    }

    float v[8];
    {
        int col0 = lane * 8;
#pragma unroll
        for (int k = 0; k < 8; ++k) v[k] = (col0 + k == 0) ? 0.f : NEG_INF_;
    }

    for (int sg = 0; sg < nsg; ++sg) {
        __syncthreads();   // half sg&1 filled; half (sg+1)&1 free

        if (wid > 0) {
            // ---- producers: fill half (sg+1)&1 with rows of phase sg+1 ----
            int sgn = sg + 1;
            if (sgn < nsg) {
                int w = wid - 1;
                int row0 = sgn * 32 + 8 * w;   // < nsg*32 <= 2048, in-bounds
                float* lb = stage + ((sgn & 1) * 16384) + (8 * w) * 512 + lane * 4;
                const float* gp = ncb + (size_t)row0 * TX_ + lane * 8;
                float4 t[16];
#pragma unroll
                for (int r = 0; r < 8; ++r) {
                    t[2 * r]     = *(const float4*)(gp + (size_t)r * TX_);
                    t[2 * r + 1] = *(const float4*)(gp + (size_t)r * TX_ + 4);
                }
#pragma unroll
                for (int r = 0; r < 8; ++r) {
                    *(float4*)(lb + r * 512)       = t[2 * r];
                    *(float4*)(lb + r * 512 + 256) = t[2 * r + 1];
                }
            }
        } else {
            // ---- consumer: DP over 32 rows, 2-group register dbuf ----
            const float* hb = stage + (sg & 1) * 16384 + lane * 4;
            float4 qa[16], qb[16];
            LOADQ(qa, hb, 0);
            LOADQ(qb, hb, 1);
            PROCQ(qa, sg * 4 + 0);
            LOADQ(qa, hb, 2);
            PROCQ(qb, sg * 4 + 1);
            LOADQ(qb, hb, 3);
            PROCQ(qa, sg * 4 + 2);
            PROCQ(qb, sg * 4 + 3);
            // dirn stores drain at the phase barrier (amortized)
        }
    }

    __syncthreads();   // forward done everywhere

    // reload dirn bits into LDS (both halves free now; layout identical to
    // the original sdirs32 layout the backward walk expects)
    {
        const float4* g4 = (const float4*)gd32;
        float4* s4 = (float4*)sdirs;
        for (int i = tid; i < TY_ * 16 / 4; i += 320) s4[i] = g4[i];
    }
    __syncthreads();

    int* pb = path + b * TY_;
    for (int j = t_y + tid; j < TY_; j += 320) pb[j] = -1;

    if (tid == 0) {
        int idx = t_x - 1;
        int j   = t_y - 1;
        while (j >= 0) {
            int n  = (j + 1 < 8) ? (j + 1) : 8;
            int bs = (idx - 7) >> 3; if (bs < 0) bs = 0;
            int b2 = bs + 1;         if (b2 > 63) b2 = 63;
            unsigned lo[8], hi[8];
#pragma unroll
            for (int r = 0; r < 8; ++r) {
                if (r < n) {
                    int jr = j - r;
                    int rb = (jr >> 2) * 256 + (jr & 3);
                    lo[r] = sdirs[rb + bs * 4];
                    hi[r] = sdirs[rb + b2 * 4];
                }
            }
#pragma unroll
            for (int r = 0; r < 8; ++r) {
                if (r < n) {
                    pb[j - r] = idx;
                    int Bi = idx >> 3;
                    unsigned byte = (Bi == bs) ? lo[r] : hi[r];
                    idx -= (int)((byte >> (idx & 7)) & 1u);
                }
            }
            j -= n;
        }
    }
}

// ---------------------------------------------------------------------------
// K4a: attn one-hot write (overwrites the neg_cent scratch region).
// ---------------------------------------------------------------------------
__global__ __launch_bounds__(256) void k_attn(const int* __restrict__ path,
                                              float* __restrict__ attn) {
    int i   = blockIdx.x * 256 + threadIdx.x;   // over B*TY*TX/4
    int tx0 = (i & 127) << 2;                   // TX/4 = 128
    int bty = i >> 7;                           // b*TY + ty
    int p   = path[bty];
    float4 o;
    o.x = (p == tx0)     ? 1.f : 0.f;
    o.y = (p == tx0 + 1) ? 1.f : 0.f;
    o.z = (p == tx0 + 2) ? 1.f : 0.f;
    o.w = (p == tx0 + 3) ? 1.f : 0.f;
    ((float4*)attn)[i] = o;
}

// ---------------------------------------------------------------------------
// K4b: m_p_a / logs_p_a gather: out[b,c,ty] = (path[ty]>=0) ? in[b,c,path] : 0
// ---------------------------------------------------------------------------
__global__ __launch_bounds__(256) void k_proj(const int* __restrict__ path,
                                              const float* __restrict__ mp,
                                              const float* __restrict__ logsp,
                                              float* __restrict__ mpa,
                                              float* __restrict__ logsa) {
    int i   = blockIdx.x * 256 + threadIdx.x;   // over B*C*TY/4
    int ty0 = (i & 511) << 2;                   // TY/4 = 512
    int bc  = i >> 9;                           // b*C + c
    int b   = bc / C_;
    const int4 p4 = *(const int4*)(path + b * TY_ + ty0);
    const float* mrow = mp    + (size_t)bc * TX_;
    const float* lrow = logsp + (size_t)bc * TX_;
    float4 mo, lo;
    mo.x = (p4.x >= 0) ? mrow[p4.x] : 0.f;  lo.x = (p4.x >= 0) ? lrow[p4.x] : 0.f;
    mo.y = (p4.y >= 0) ? mrow[p4.y] : 0.f;  lo.y = (p4.y >= 0) ? lrow[p4.y] : 0.f;
    mo.z = (p4.z >= 0) ? mrow[p4.z] : 0.f;  lo.z = (p4.z >= 0) ? lrow[p4.z] : 0.f;
    mo.w = (p4.w >= 0) ? mrow[p4.w] : 0.f;  lo.w = (p4.w >= 0) ? lrow[p4.w] : 0.f;
    ((float4*)mpa)[i]   = mo;
    ((float4*)logsa)[i] = lo;
}

// ---------------------------------------------------------------------------
// K4c: random segment slice of z + ids output (replicates ref f32 math).
// ---------------------------------------------------------------------------
__global__ __launch_bounds__(256) void k_slice(const float* __restrict__ z,
                                               const int* __restrict__ yl,
                                               const float* __restrict__ ru,
                                               float* __restrict__ zs,
                                               float* __restrict__ oid) {
    int b = blockIdx.x;
    int safe = yl[b]; if (safe > TY_) safe = TY_;
    int idsmax = safe - SEG_; if (idsmax < 0) idsmax = 0;
    int ids = (int)(ru[b] * ((float)idsmax + 1e-8f));
    int lim = safe - ids;
    for (int t = threadIdx.x; t < C_ * SEG_; t += 256) {
        int c = t >> 5, k = t & 31;
        zs[b * C_ * SEG_ + t] =
            (k < lim) ? z[((size_t)b * C_ + c) * TY_ + ids + k] : 0.f;
    }
    if (threadIdx.x == 0) oid[b] = (float)ids;
}

// ---------------------------------------------------------------------------
extern "C" void kernel_launch(void* const* d_in, const int* in_sizes, int n_in,
                              void* d_out, int out_size, void* d_ws, size_t ws_size,
                              hipStream_t stream) {
    const float* z     = (const float*)d_in[0];
    const float* zp    = (const float*)d_in[1];
    const float* mp    = (const float*)d_in[2];
    const float* logsp = (const float*)d_in[3];
    const int*   xl    = (const int*)d_in[4];
    const int*   yl    = (const int*)d_in[5];
    const float* ru    = (const float*)d_in[6];

    float* out     = (float*)d_out;
    float* o_zs    = out;                  // 98304
    float* o_ids   = out + 98304;          // 16
    float* o_attn  = out + 98320;          // 16777216 (also neg_cent scratch)
    float* o_mpa   = out + 16875536;       // 6291456
    float* o_logsa = out + 23166992;       // 6291456

    float* Bmat  = (float*)d_ws;                        // 3,145,728 f
    float* cterm = Bmat + (size_t)B_ * K_ * TX_;        // 8192 f
    int*   path  = (int*)(cterm + B_ * TX_);            // 32768 i32
    int*   gdirs = (int*)o_mpa;   // 2 MB dirn scratch; k_proj overwrites later

    // allow 128 KiB dynamic LDS for the fused DP kernel (host-side, not a
    // stream op — safe under graph capture; idempotent, called every launch)
    hipFuncSetAttribute((const void*)k_dp,
                        hipFuncAttributeMaxDynamicSharedMemorySize,
                        TY_ * 64);

    hipLaunchKernelGGL(k_prep, dim3(TX_ / 128, B_), dim3(128), 0, stream,
                       mp, logsp, Bmat, cterm);
    hipLaunchKernelGGL(k_gemm, dim3(TX_ / 128, TY_ / 128, B_), dim3(256), 0, stream,
                       zp, Bmat, cterm, o_attn);
    hipLaunchKernelGGL(k_dp, dim3(B_), dim3(320), TY_ * 64, stream,
                       o_attn, xl, yl, path, gdirs);
    hipLaunchKernelGGL(k_attn, dim3(B_ * TY_ * TX_ / 4 / 256), dim3(256), 0, stream,
                       path, o_attn);
    hipLaunchKernelGGL(k_proj, dim3(B_ * C_ * TY_ / 4 / 256), dim3(256), 0, stream,
                       path, mp, logsp, o_mpa, o_logsa);
    hipLaunchKernelGGL(k_slice, dim3(B_), dim3(256), 0, stream,
                       z, yl, ru, o_zs, o_ids);
}

// Round 9
// 714.662 us; speedup vs baseline: 1.0890x; 1.0890x over previous
//
#include <hip/hip_runtime.h>
#include <stdint.h>

#define B_   16
#define C_   192
#define TX_  512
#define TY_  2048
#define K_   384       // 2*C
#define SEG_ 32
#define NEG_INF_ (-1e9f)

typedef float f32x4 __attribute__((ext_vector_type(4)));

// Output layout (floats) in d_out:
//   z_slice : [16,192,32]    @ 0         (98304)
//   ids     : [16] (as f32)  @ 98304     (16)
//   attn    : [16,2048,512]  @ 98320     (16777216)
//   m_p_a   : [16,192,2048]  @ 16875536  (6291456)
//   logs_p_a: [16,192,2048]  @ 23166992  (6291456)

// ---------------------------------------------------------------------------
// K0: build B-matrix [b, k, tx] (k<192: s = exp(-2 logs); k>=192: s*m_p) and
//     c_term[b,tx] = sum_c (-0.5 s m^2 - logs)
// ---------------------------------------------------------------------------
__global__ __launch_bounds__(128) void k_prep(const float* __restrict__ mp,
                                              const float* __restrict__ logsp,
                                              float* __restrict__ Bmat,
                                              float* __restrict__ cterm) {
    int b  = blockIdx.y;
    int tx = blockIdx.x * 128 + threadIdx.x;
    const float* mb = mp    + (size_t)b * C_ * TX_ + tx;
    const float* lb = logsp + (size_t)b * C_ * TX_ + tx;
    float* B0 = Bmat + (size_t)b * K_ * TX_ + tx;
    float acc = 0.f;
    for (int c = 0; c < C_; ++c) {
        float lg = lb[(size_t)c * TX_];
        float m  = mb[(size_t)c * TX_];
        float s  = expf(-2.f * lg);
        B0[(size_t)c * TX_]        = s;
        B0[(size_t)(C_ + c) * TX_] = s * m;
        acc += -0.5f * s * m * m - lg;
    }
    cterm[b * TX_ + tx] = acc;
}

// ---------------------------------------------------------------------------
// K1: neg_cent GEMM.  C[b, ty, tx] = sum_k A[b,k,ty]*B[b,k,tx] + cterm[b,tx]
//     A is derived on the fly from z_p: k<192 -> -0.5*z^2 ; k>=192 -> z.
//     128x128 tile, 256 threads, 8x8 accumulators/thread, K-block 16.
// ---------------------------------------------------------------------------
__global__ __launch_bounds__(256) void k_gemm(const float* __restrict__ zp,
                                              const float* __restrict__ Bmat,
                                              const float* __restrict__ cterm,
                                              float* __restrict__ ncout) {
    __shared__ float As[16][128];
    __shared__ float Bs[16][128];
    int b  = blockIdx.z;
    int m0 = blockIdx.y * 128;   // ty
    int n0 = blockIdx.x * 128;   // tx
    int tid = threadIdx.x;
    int tm = tid >> 4;           // 0..15
    int tn = tid & 15;           // 0..15
    const float* zpb = zp   + (size_t)b * C_ * TY_;
    const float* Bb  = Bmat + (size_t)b * K_ * TX_;

    float acc[8][8];
#pragma unroll
    for (int i = 0; i < 8; ++i)
#pragma unroll
        for (int j = 0; j < 8; ++j) acc[i][j] = 0.f;

    int lrow = tid >> 5;           // 0..7
    int lcol = (tid & 31) << 2;    // 0..124

    for (int k0 = 0; k0 < K_; k0 += 16) {
        int ksrc = (k0 < C_) ? k0 : (k0 - C_);
        const float* Ab = zpb + (size_t)(ksrc + lrow) * TY_ + m0 + lcol;
        float4 z0 = *(const float4*)Ab;
        float4 z1 = *(const float4*)(Ab + (size_t)8 * TY_);
        if (k0 < C_) {
            z0.x = -0.5f * z0.x * z0.x; z0.y = -0.5f * z0.y * z0.y;
            z0.z = -0.5f * z0.z * z0.z; z0.w = -0.5f * z0.w * z0.w;
            z1.x = -0.5f * z1.x * z1.x; z1.y = -0.5f * z1.y * z1.y;
            z1.z = -0.5f * z1.z * z1.z; z1.w = -0.5f * z1.w * z1.w;
        }
        const float* Bp = Bb + (size_t)(k0 + lrow) * TX_ + n0 + lcol;
        float4 w0 = *(const float4*)Bp;
        float4 w1 = *(const float4*)(Bp + (size_t)8 * TX_);

        __syncthreads();   // prior iteration's reads done before overwrite
        *(float4*)&As[lrow][lcol]     = z0;
        *(float4*)&As[lrow + 8][lcol] = z1;
        *(float4*)&Bs[lrow][lcol]     = w0;
        *(float4*)&Bs[lrow + 8][lcol] = w1;
        __syncthreads();

#pragma unroll
        for (int kk = 0; kk < 16; ++kk) {
            float4 a0 = *(const float4*)&As[kk][tm * 8];
            float4 a1 = *(const float4*)&As[kk][tm * 8 + 4];
            float4 b0 = *(const float4*)&Bs[kk][tn * 8];
            float4 b1 = *(const float4*)&Bs[kk][tn * 8 + 4];
            float a[8]  = {a0.x, a0.y, a0.z, a0.w, a1.x, a1.y, a1.z, a1.w};
            float bb[8] = {b0.x, b0.y, b0.z, b0.w, b1.x, b1.y, b1.z, b1.w};
#pragma unroll
            for (int i = 0; i < 8; ++i)
#pragma unroll
                for (int j = 0; j < 8; ++j)
                    acc[i][j] = fmaf(a[i], bb[j], acc[i][j]);
        }
    }

    float cadd[8];
#pragma unroll
    for (int j = 0; j < 8; ++j) cadd[j] = cterm[b * TX_ + n0 + tn * 8 + j];

#pragma unroll
    for (int i = 0; i < 8; ++i) {
        int row = m0 + tm * 8 + i;
        float* orow = ncout + ((size_t)b * TY_ + row) * TX_ + n0 + tn * 8;
        float4 o0, o1;
        o0.x = acc[i][0] + cadd[0]; o0.y = acc[i][1] + cadd[1];
        o0.z = acc[i][2] + cadd[2]; o0.w = acc[i][3] + cadd[3];
        o1.x = acc[i][4] + cadd[4]; o1.y = acc[i][5] + cadd[5];
        o1.z = acc[i][6] + cadd[6]; o1.w = acc[i][7] + cadd[7];
        *(float4*)orow       = o0;
        *(float4*)(orow + 4) = o1;
    }
}

// ---------------------------------------------------------------------------
// K2: fused DP forward + backward. Barrier-phased + asm-batched reads (r9).
//
// History (cyc/row): r0 496 (sunk global loads), r3 621 (single-wave DMA),
// r6 497 (flag protocol flat-polls), r7 ~450 (barrier-phased, loads sunk),
// r8 ~487 (sched_barrier did NOT batch: VGPR_Count=44 vs 128 needed — the
// compiler re-interleaved load/use anyway). Model: with loads sunk, each
// row pays ~2 serialized lgkm waits (~120cyc each, m117) + ~45 VALU.
// Source-level batching is unobtainable from this compiler.
//
// r9: consume each 8-row group via ONE inline-asm block: 16x ds_read_b128
// (offsets 0..15360 step 1024) + s_waitcnt lgkmcnt(0) as the LAST
// instruction of the SAME block. Outputs are 16 early-clobber f32x4 regs:
// the compiler MUST materialize them (~64 VGPRs), and because the wait is
// inside the block, every output is architecturally complete before any
// compiler-inserted copy can run (r1's deferred-def hazard cannot occur).
// One exposed LDS latency per group (~250cyc incl. pipelined reads, m134)
// = ~30 cyc/row amortized.
//
// Structure reverts to r7's better config: block = 9 waves (576 thr),
// wave 0 consumer, waves 1..8 producers 4 rows each/phase. LDS = 2 x 64KB
// halves (32 rows x 2KB); phase sg: producers fill half (sg+1)&1, consumer
// drains half sg&1 (4 asm groups), one barrier per phase. Dirn dwords ->
// gdirs (= m_p_a region, overwritten later by k_proj), drained at the
// phase barrier. After forward, all waves copy gdirs into LDS (original
// layout); proven backward walk unchanged. Rows >= t_y are processed as
// harmless garbage (their dirn bits are never consulted).
// ---------------------------------------------------------------------------
#if __has_builtin(__builtin_amdgcn_update_dpp)
// wave_shr:1 (dpp_ctrl 0x138): lane L <- lane L-1; lane 0 <- old (=NEG_INF).
#define LEFT_OF(v7)                                                          \
    __int_as_float(__builtin_amdgcn_update_dpp(                              \
        __float_as_int(NEG_INF_), __float_as_int(v7), 0x138, 0xF, 0xF, false))
#else
#define LEFT_OF(v7)                                                         \
    ({ float _l = __shfl_up((v7), 1); if (lane == 0) _l = NEG_INF_; _l; })
#endif

// One 8-row group: 16x ds_read_b128 + wait, atomically in one asm block.
// qq[k] <- LDS[addr + k*1024]  (k = 2r   -> row r cols 0..3 of this lane,
//                               k = 2r+1 -> row r cols 4..7)
#define DS_READ_GROUP(qq, addr)                                              \
    asm volatile(                                                            \
        "ds_read_b128 %0,  %16 offset:0\n\t"                                 \
        "ds_read_b128 %1,  %16 offset:1024\n\t"                              \
        "ds_read_b128 %2,  %16 offset:2048\n\t"                              \
        "ds_read_b128 %3,  %16 offset:3072\n\t"                              \
        "ds_read_b128 %4,  %16 offset:4096\n\t"                              \
        "ds_read_b128 %5,  %16 offset:5120\n\t"                              \
        "ds_read_b128 %6,  %16 offset:6144\n\t"                              \
        "ds_read_b128 %7,  %16 offset:7168\n\t"                              \
        "ds_read_b128 %8,  %16 offset:8192\n\t"                              \
        "ds_read_b128 %9,  %16 offset:9216\n\t"                              \
        "ds_read_b128 %10, %16 offset:10240\n\t"                             \
        "ds_read_b128 %11, %16 offset:11264\n\t"                             \
        "ds_read_b128 %12, %16 offset:12288\n\t"                             \
        "ds_read_b128 %13, %16 offset:13312\n\t"                             \
        "ds_read_b128 %14, %16 offset:14336\n\t"                             \
        "ds_read_b128 %15, %16 offset:15360\n\t"                             \
        "s_waitcnt lgkmcnt(0)"                                               \
        : "=&v"(qq[0]),  "=&v"(qq[1]),  "=&v"(qq[2]),  "=&v"(qq[3]),         \
          "=&v"(qq[4]),  "=&v"(qq[5]),  "=&v"(qq[6]),  "=&v"(qq[7]),         \
          "=&v"(qq[8]),  "=&v"(qq[9]),  "=&v"(qq[10]), "=&v"(qq[11]),        \
          "=&v"(qq[12]), "=&v"(qq[13]), "=&v"(qq[14]), "=&v"(qq[15])         \
        : "v"(addr)                                                          \
        : "memory")

__global__ __launch_bounds__(576, 1) void k_dp(const float* __restrict__ nc,
                                               const int* __restrict__ xl,
                                               const int* __restrict__ yl,
                                               int* __restrict__ path,
                                               int* __restrict__ gdirs) {
    extern __shared__ unsigned char sdirs[];   // 131072 B: 2 x 64KB halves
    float* stage = (float*)sdirs;              // half h at float offset h*16384
    int b    = blockIdx.x;
    int tid  = threadIdx.x;
    int wid  = tid >> 6;                       // 0 = consumer, 1..8 producers
    int lane = tid & 63;
    int t_x  = xl[b];
    int t_y  = yl[b]; if (t_y > TY_) t_y = TY_;
    const float* ncb = nc + (size_t)b * TY_ * TX_;
    int* gd32 = gdirs + b * (TY_ * 64 / 4);    // 32768 dwords per block

    int nsg = (t_y + 31) >> 5;                 // 32-row phases

    // ---- prologue: producers fill half 0 with rows 0..31 (4 rows each) ----
    if (wid > 0) {
        int w = wid - 1;
        float* lb = stage + (4 * w) * 512 + lane * 4;
        const float* gp = ncb + (size_t)(4 * w) * TX_ + lane * 8;
#pragma unroll
        for (int r = 0; r < 4; ++r) {
            float4 a = *(const float4*)(gp + (size_t)r * TX_);
            float4 c = *(const float4*)(gp + (size_t)r * TX_ + 4);
            *(float4*)(lb + r * 512)       = a;
            *(float4*)(lb + r * 512 + 256) = c;
        }
    }

    float v[8];
    {
        int col0 = lane * 8;
#pragma unroll
        for (int k = 0; k < 8; ++k) v[k] = (col0 + k == 0) ? 0.f : NEG_INF_;
    }

    for (int sg = 0; sg < nsg; ++sg) {
        __syncthreads();   // half sg&1 filled; half (sg+1)&1 free

        if (wid > 0) {
            // ---- producers: fill half (sg+1)&1 with rows of phase sg+1 ----
            int sgn = sg + 1;
            if (sgn < nsg) {
                int w = wid - 1;
                int row0 = sgn * 32 + 4 * w;   // < nsg*32 <= 2048, in-bounds
                float* lb = stage + ((sgn & 1) * 16384) + (4 * w) * 512 + lane * 4;
                const float* gp = ncb + (size_t)row0 * TX_ + lane * 8;
#pragma unroll
                for (int r = 0; r < 4; ++r) {
                    float4 a = *(const float4*)(gp + (size_t)r * TX_);
                    float4 c = *(const float4*)(gp + (size_t)r * TX_ + 4);
                    *(float4*)(lb + r * 512)       = a;
                    *(float4*)(lb + r * 512 + 256) = c;
                }
            }
        } else {
            // ---- consumer: 4 asm-batched groups of 8 rows ----
            unsigned hbase = (unsigned)((sg & 1) * 65536 + lane * 16);
            f32x4 qq[16];
#pragma unroll
            for (int g = 0; g < 4; ++g) {
                unsigned addr = hbase + (unsigned)(g * 16384);
                DS_READ_GROUP(qq, addr);
                unsigned dw0 = 0u, dw1 = 0u;
#pragma unroll
                for (int r = 0; r < 8; ++r) {
                    float rc[8] = {qq[2 * r][0],     qq[2 * r][1],
                                   qq[2 * r][2],     qq[2 * r][3],
                                   qq[2 * r + 1][0], qq[2 * r + 1][1],
                                   qq[2 * r + 1][2], qq[2 * r + 1][3]};
                    float left = LEFT_OF(v[7]);
                    unsigned by = 0u;
#pragma unroll
                    for (int k = 7; k >= 0; --k) {
                        float vs = (k == 0) ? left : v[k - 1];
                        if (vs > v[k]) by |= (1u << k);
                        v[k] = fmaxf(v[k], vs) + rc[k];
                    }
                    if (r < 4) dw0 |= by << (8 * r);
                    else       dw1 |= by << (8 * (r - 4));
                }
                int gidx = sg * 4 + g;
                gd32[(2 * gidx)     * 64 + lane] = (int)dw0;   // fire-and-forget;
                gd32[(2 * gidx + 1) * 64 + lane] = (int)dw1;   // drains at barrier
            }
        }
    }

    __syncthreads();   // forward done everywhere

    // reload dirn bits into LDS (both halves free now; layout identical to
    // the original sdirs32 layout the backward walk expects)
    {
        const float4* g4 = (const float4*)gd32;
        float4* s4 = (float4*)sdirs;
        for (int i = tid; i < TY_ * 16 / 4; i += 576) s4[i] = g4[i];
    }
    __syncthreads();

    int* pb = path + b * TY_;
    for (int j = t_y + tid; j < TY_; j += 576) pb[j] = -1;

    if (tid == 0) {
        int idx = t_x - 1;
        int j   = t_y - 1;
        while (j >= 0) {
            int n  = (j + 1 < 8) ? (j + 1) : 8;
            int bs = (idx - 7) >> 3; if (bs < 0) bs = 0;
            int b2 = bs + 1;         if (b2 > 63) b2 = 63;
            unsigned lo[8], hi[8];
#pragma unroll
            for (int r = 0; r < 8; ++r) {
                if (r < n) {
                    int jr = j - r;
                    int rb = (jr >> 2) * 256 + (jr & 3);
                    lo[r] = sdirs[rb + bs * 4];
                    hi[r] = sdirs[rb + b2 * 4];
                }
            }
#pragma unroll
            for (int r = 0; r < 8; ++r) {
                if (r < n) {
                    pb[j - r] = idx;
                    int Bi = idx >> 3;
                    unsigned byte = (Bi == bs) ? lo[r] : hi[r];
                    idx -= (int)((byte >> (idx & 7)) & 1u);
                }
            }
            j -= n;
        }
    }
}

// ---------------------------------------------------------------------------
// K4a: attn one-hot write (overwrites the neg_cent scratch region).
// ---------------------------------------------------------------------------
__global__ __launch_bounds__(256) void k_attn(const int* __restrict__ path,
                                              float* __restrict__ attn) {
    int i   = blockIdx.x * 256 + threadIdx.x;   // over B*TY*TX/4
    int tx0 = (i & 127) << 2;                   // TX/4 = 128
    int bty = i >> 7;                           // b*TY + ty
    int p   = path[bty];
    float4 o;
    o.x = (p == tx0)     ? 1.f : 0.f;
    o.y = (p == tx0 + 1) ? 1.f : 0.f;
    o.z = (p == tx0 + 2) ? 1.f : 0.f;
    o.w = (p == tx0 + 3) ? 1.f : 0.f;
    ((float4*)attn)[i] = o;
}

// ---------------------------------------------------------------------------
// K4b: m_p_a / logs_p_a gather: out[b,c,ty] = (path[ty]>=0) ? in[b,c,path] : 0
// ---------------------------------------------------------------------------
__global__ __launch_bounds__(256) void k_proj(const int* __restrict__ path,
                                              const float* __restrict__ mp,
                                              const float* __restrict__ logsp,
                                              float* __restrict__ mpa,
                                              float* __restrict__ logsa) {
    int i   = blockIdx.x * 256 + threadIdx.x;   // over B*C*TY/4
    int ty0 = (i & 511) << 2;                   // TY/4 = 512
    int bc  = i >> 9;                           // b*C + c
    int b   = bc / C_;
    const int4 p4 = *(const int4*)(path + b * TY_ + ty0);
    const float* mrow = mp    + (size_t)bc * TX_;
    const float* lrow = logsp + (size_t)bc * TX_;
    float4 mo, lo;
    mo.x = (p4.x >= 0) ? mrow[p4.x] : 0.f;  lo.x = (p4.x >= 0) ? lrow[p4.x] : 0.f;
    mo.y = (p4.y >= 0) ? mrow[p4.y] : 0.f;  lo.y = (p4.y >= 0) ? lrow[p4.y] : 0.f;
    mo.z = (p4.z >= 0) ? mrow[p4.z] : 0.f;  lo.z = (p4.z >= 0) ? lrow[p4.z] : 0.f;
    mo.w = (p4.w >= 0) ? mrow[p4.w] : 0.f;  lo.w = (p4.w >= 0) ? lrow[p4.w] : 0.f;
    ((float4*)mpa)[i]   = mo;
    ((float4*)logsa)[i] = lo;
}

// ---------------------------------------------------------------------------
// K4c: random segment slice of z + ids output (replicates ref f32 math).
// ---------------------------------------------------------------------------
__global__ __launch_bounds__(256) void k_slice(const float* __restrict__ z,
                                               const int* __restrict__ yl,
                                               const float* __restrict__ ru,
                                               float* __restrict__ zs,
                                               float* __restrict__ oid) {
    int b = blockIdx.x;
    int safe = yl[b]; if (safe > TY_) safe = TY_;
    int idsmax = safe - SEG_; if (idsmax < 0) idsmax = 0;
    int ids = (int)(ru[b] * ((float)idsmax + 1e-8f));
    int lim = safe - ids;
    for (int t = threadIdx.x; t < C_ * SEG_; t += 256) {
        int c = t >> 5, k = t & 31;
        zs[b * C_ * SEG_ + t] =
            (k < lim) ? z[((size_t)b * C_ + c) * TY_ + ids + k] : 0.f;
    }
    if (threadIdx.x == 0) oid[b] = (float)ids;
}

// ---------------------------------------------------------------------------
extern "C" void kernel_launch(void* const* d_in, const int* in_sizes, int n_in,
                              void* d_out, int out_size, void* d_ws, size_t ws_size,
                              hipStream_t stream) {
    const float* z     = (const float*)d_in[0];
    const float* zp    = (const float*)d_in[1];
    const float* mp    = (const float*)d_in[2];
    const float* logsp = (const float*)d_in[3];
    const int*   xl    = (const int*)d_in[4];
    const int*   yl    = (const int*)d_in[5];
    const float* ru    = (const float*)d_in[6];

    float* out     = (float*)d_out;
    float* o_zs    = out;                  // 98304
    float* o_ids   = out + 98304;          // 16
    float* o_attn  = out + 98320;          // 16777216 (also neg_cent scratch)
    float* o_mpa   = out + 16875536;       // 6291456
    float* o_logsa = out + 23166992;       // 6291456

    float* Bmat  = (float*)d_ws;                        // 3,145,728 f
    float* cterm = Bmat + (size_t)B_ * K_ * TX_;        // 8192 f
    int*   path  = (int*)(cterm + B_ * TX_);            // 32768 i32
    int*   gdirs = (int*)o_mpa;   // 2 MB dirn scratch; k_proj overwrites later

    // allow 128 KiB dynamic LDS for the fused DP kernel (host-side, not a
    // stream op — safe under graph capture; idempotent, called every launch)
    hipFuncSetAttribute((const void*)k_dp,
                        hipFuncAttributeMaxDynamicSharedMemorySize,
                        TY_ * 64);

    hipLaunchKernelGGL(k_prep, dim3(TX_ / 128, B_), dim3(128), 0, stream,
                       mp, logsp, Bmat, cterm);
    hipLaunchKernelGGL(k_gemm, dim3(TX_ / 128, TY_ / 128, B_), dim3(256), 0, stream,
                       zp, Bmat, cterm, o_attn);
    hipLaunchKernelGGL(k_dp, dim3(B_), dim3(576), TY_ * 64, stream,
                       o_attn, xl, yl, path, gdirs);
    hipLaunchKernelGGL(k_attn, dim3(B_ * TY_ * TX_ / 4 / 256), dim3(256), 0, stream,
                       path, o_attn);
    hipLaunchKernelGGL(k_proj, dim3(B_ * C_ * TY_ / 4 / 256), dim3(256), 0, stream,
                       path, mp, logsp, o_mpa, o_logsa);
    hipLaunchKernelGGL(k_slice, dim3(B_), dim3(256), 0, stream,
                       z, yl, ru, o_zs, o_ids);
}